// Round 10
// baseline (102.075 us; speedup 1.0000x reference)
//
#include <hip/hip_runtime.h>
#include <math.h>

#define BSZ 512
#define DD 2048
#define KK 128
#define PP 5
#define NCOL (KK * PP)   // 640
#define OUTW (DD + KK)   // 2176
#define LOG2E 1.4426950408889634f

#define KSPLIT 16
#define GK (DD / KSPLIT) // 128 k-depth per split

typedef __attribute__((ext_vector_type(8))) short bf16x8;
typedef __attribute__((ext_vector_type(4))) float f32x4;

// ws layout (floats):
#define WS_NORM 0
#define WS_ACTV (WS_NORM + NCOL)                      // 640  ([k][512][5] layout)
#define WS_XB (WS_ACTV + BSZ * NCOL)                  // 328320 (512*2048 ushort)
#define WS_THT (WS_XB + BSZ * DD / 2)                 // 852608 (640*2048 ushort)
#define WS_PART (WS_THT + NCOL * DD / 2)              // 1507968 (16*512*640 ushort)

__device__ inline ushort f2b(float f) {               // f32 -> bf16 RNE
    unsigned u = __float_as_uint(f);
    u += 0x7FFF + ((u >> 16) & 1);
    return (ushort)(u >> 16);
}

// XOR-swizzled LDS index (ushort units).
#define SWZ(r, c) ((((r) * 128) + ((c) ^ (((r) & 7) << 3))))

// ---------------------------------------------------------------------------
// Kernel 1 (prep): [0,80) norm = colsum theta^2; [80,400) theta -> bf16
// transposed [640 n][2048 k]; [400,656) x -> bf16 [512][2048].
// ---------------------------------------------------------------------------
__global__ __launch_bounds__(256) void prep_kernel(const float* __restrict__ theta,
                                                   const float* __restrict__ x,
                                                   float* __restrict__ norm,
                                                   ushort* __restrict__ thT,
                                                   ushort* __restrict__ xb) {
    __shared__ float partial[32][8];
    __shared__ ushort sT[64][68];   // [n][k] tile; stride 68: write 8-way, read 2-way

    const int bid = blockIdx.x;
    const int t   = threadIdx.x;

    if (bid < 80) {                 // ---- norm ----
        const int c8  = bid * 8;
        const int col = c8 + (t & 7);
        const int g   = t >> 3;
        const float* p = theta + (size_t)g * NCOL + col;
        float s = 0.f;
#pragma unroll
        for (int j = 0; j < 64; ++j) {
            float v = p[(size_t)j * 32 * NCOL];
            s += v * v;
        }
        partial[g][t & 7] = s;
        __syncthreads();
        if (t < 8) {
            float acc = 0.f;
#pragma unroll
            for (int gg = 0; gg < 32; ++gg) acc += partial[gg][t];
            norm[c8 + t] = acc;
        }
    } else if (bid < 400) {         // ---- theta transpose+convert, 64x64 tiles ----
        const int tb    = bid - 80;        // 0..319 = 32 ktiles x 10 ntiles
        const int kz    = (tb & 31) * 64;
        const int nz    = (tb >> 5) * 64;
        const int c4    = t & 15;          // n-quad
        const int rbase = t >> 4;          // k-row base
#pragma unroll
        for (int i = 0; i < 4; ++i) {
            int r = rbase + i * 16;
            float4 v = *(const float4*)&theta[(size_t)(kz + r) * NCOL + nz + c4 * 4];
            sT[c4 * 4 + 0][r] = f2b(v.x);
            sT[c4 * 4 + 1][r] = f2b(v.y);
            sT[c4 * 4 + 2][r] = f2b(v.z);
            sT[c4 * 4 + 3][r] = f2b(v.w);
        }
        __syncthreads();
#pragma unroll
        for (int i = 0; i < 2; ++i) {
            int slot = t + i * 256;
            int rr   = slot >> 3;          // n row 0..63
            int cc   = (slot & 7) * 8;     // k col
            ushort4 w0 = *(const ushort4*)&sT[rr][cc];
            ushort4 w1 = *(const ushort4*)&sT[rr][cc + 4];
            ushort* dst = &thT[(size_t)(nz + rr) * DD + kz + cc];
            *(ushort4*)&dst[0] = w0;
            *(ushort4*)&dst[4] = w1;
        }
    } else {                        // ---- x convert ----
        const int b2 = bid - 400;          // 0..255
#pragma unroll
        for (int i = 0; i < 4; ++i) {
            int base = b2 * 4096 + i * 1024 + t * 4;
            float4 v = *(const float4*)&x[base];
            ushort4 w;
            w.x = f2b(v.x); w.y = f2b(v.y); w.z = f2b(v.z); w.w = f2b(v.w);
            *(ushort4*)&xb[base] = w;
        }
    }
}

// ---------------------------------------------------------------------------
// Kernel 2: split-K MFMA GEMM, ONE chunk per block (1280 blocks = 5/CU all
// resident; r7-verified). XCD swizzle: m-tile = bid&7 -> per-XCD set 2.75MB
// < 4MB L2. part stored bf16 (r8-verified, absmax unchanged).
// Blocks [1280,1360): x -> out[:, :D] copy.
// ---------------------------------------------------------------------------
__global__ __launch_bounds__(256) void gemm_kernel(const ushort* __restrict__ xb,
                                                   const ushort* __restrict__ thT,
                                                   ushort* __restrict__ parth,
                                                   const float* __restrict__ x,
                                                   float* __restrict__ out) {
    __shared__ ushort lA[64 * 128];   // 16 KiB, swizzled
    __shared__ ushort lB[64 * 128];

    const int bx = blockIdx.x;
    if (bx >= 1280) {
        const int bid = bx - 1280;      // 0..79
        for (int i = bid * 256 + threadIdx.x; i < BSZ * (DD / 4); i += 80 * 256) {
            int r = i >> 9;
            int c = i & 511;
            float4 v = *(const float4*)&x[(size_t)r * DD + c * 4];
            *(float4*)&out[(size_t)r * OUTW + c * 4] = v;
        }
        return;
    }

    const int t    = threadIdx.x;
    const int lane = t & 63;
    const int wave = t >> 6;
    const int mt8  = bx & 7;           // m-tile -> XCD affinity
    const int rest = bx >> 3;          // 0..159
    const int bn   = (rest % 10) * 64;
    const int bm   = mt8 * 64;
    const int z    = rest / 10;        // 0..15
    const int kz   = z * GK;

    const ushort* gA = xb  + (size_t)bm * DD + kz;
    const ushort* gB = thT + (size_t)bn * DD + kz;

    const int srr = t >> 4;          // staging row base
    const int sss = t & 15;          // staging slot

    uint4 va[4], vb[4];
#pragma unroll
    for (int i = 0; i < 4; ++i) {
        int rr = srr + i * 16;
        va[i] = *(const uint4*)&gA[(size_t)rr * DD + sss * 8];
        vb[i] = *(const uint4*)&gB[(size_t)rr * DD + sss * 8];
    }
#pragma unroll
    for (int i = 0; i < 4; ++i) {
        int rr = srr + i * 16;
        *(uint4*)&lA[SWZ(rr, sss * 8)] = va[i];
        *(uint4*)&lB[SWZ(rr, sss * 8)] = vb[i];
    }
    __syncthreads();

    const int fr = lane & 15;
    const int g  = lane >> 4;
    const int mr = (wave >> 1) * 32 + fr;
    const int nr = (wave & 1) * 32 + fr;

    f32x4 acc[2][2] = {};
#pragma unroll
    for (int ks = 0; ks < 4; ++ks) {
        const int kc = ks * 32 + g * 8;
        bf16x8 a0 = *(const bf16x8*)&lA[SWZ(mr,      kc)];
        bf16x8 a1 = *(const bf16x8*)&lA[SWZ(mr + 16, kc)];
        bf16x8 b0 = *(const bf16x8*)&lB[SWZ(nr,      kc)];
        bf16x8 b1 = *(const bf16x8*)&lB[SWZ(nr + 16, kc)];
        acc[0][0] = __builtin_amdgcn_mfma_f32_16x16x32_bf16(a0, b0, acc[0][0], 0, 0, 0);
        acc[0][1] = __builtin_amdgcn_mfma_f32_16x16x32_bf16(a0, b1, acc[0][1], 0, 0, 0);
        acc[1][0] = __builtin_amdgcn_mfma_f32_16x16x32_bf16(a1, b0, acc[1][0], 0, 0, 0);
        acc[1][1] = __builtin_amdgcn_mfma_f32_16x16x32_bf16(a1, b1, acc[1][1], 0, 0, 0);
    }

    // C/D map: col=lane&15, row=(lane>>4)*4+reg [m89-verified]
    ushort* base = parth + (size_t)z * (BSZ * NCOL);
#pragma unroll
    for (int mt = 0; mt < 2; ++mt)
#pragma unroll
        for (int nt = 0; nt < 2; ++nt) {
            int row = bm + (wave >> 1) * 32 + mt * 16 + g * 4;
            int col = bn + (wave & 1) * 32 + nt * 16 + fr;
            ushort* dst = base + (size_t)row * NCOL + col;
#pragma unroll
            for (int reg = 0; reg < 4; ++reg)
                dst[(size_t)reg * NCOL] = f2b(acc[mt][nt][reg]);
        }
}

// ---------------------------------------------------------------------------
// Kernel 3: reduce 16 bf16 split-K partials (ushort2 reads), fold scale,
// write actv in [k][512][5] layout (pairwise-friendly: per-k slice is
// 10KB contiguous). Reads coalesced; 20B-granular writes L2-absorbed.
// ---------------------------------------------------------------------------
__global__ __launch_bounds__(256) void reduce_kernel(const ushort* __restrict__ parth,
                                                     const float* __restrict__ norm,
                                                     const float* __restrict__ lws,
                                                     float* __restrict__ actv) {
    int i   = (blockIdx.x * 256 + threadIdx.x) * 2;   // input idx, b-major
    int b   = i / NCOL;
    int col = i - b * NCOL;                            // even
    float s0 = 0.f, s1 = 0.f;
#pragma unroll
    for (int q = 0; q < KSPLIT; ++q) {
        unsigned u = *(const unsigned*)&parth[(size_t)q * (BSZ * NCOL) + i];
        s0 += __uint_as_float(u << 16);
        s1 += __uint_as_float(u & 0xffff0000u);
    }
    const float sc0 = __builtin_amdgcn_exp2f(lws[col] * LOG2E) *
                      __builtin_amdgcn_rsqf(norm[col]) * LOG2E;
    const float sc1 = __builtin_amdgcn_exp2f(lws[col + 1] * LOG2E) *
                      __builtin_amdgcn_rsqf(norm[col + 1]) * LOG2E;
    int k0 = col / 5,       p0 = col - k0 * 5;
    int k1 = (col + 1) / 5, p1 = (col + 1) - k1 * 5;
    actv[((size_t)k0 * BSZ + b) * PP + p0] = s0 * sc0;
    actv[((size_t)k1 * BSZ + b) * PP + p1] = s1 * sc1;
}

// ---------------------------------------------------------------------------
// Kernel 4: pairwise, final-output form. Block (k, bc): rows bc*64..+64,
// ALL 512 j per block (128 j per wave), cmp rows staged ONCE in LDS
// (broadcast ds_read, conflict-free) -> 2 DS + ~12 VALU per j (r9's 5
// VMEM/j issue-bound loop eliminated). 4 wave-partials LDS-reduced, write
// out[:, D+k] directly with bias (freduce + f_part round-trip deleted).
// Diagonal j==b contributes exp2(0)=1 -> subtract 1.
// ---------------------------------------------------------------------------
__global__ __launch_bounds__(256) void pairwise_kernel(const float* __restrict__ actv,
                                                       const float* __restrict__ bias,
                                                       float* __restrict__ out) {
    const int k   = blockIdx.x;    // 0..127
    const int bc  = blockIdx.y;    // 0..7
    const int tid = threadIdx.x;   // 0..255
    const int r   = tid & 63;
    const int seg = tid >> 6;      // wave = j-segment

    __shared__ float sB[512][8];   // 16 KiB, rows 32B-aligned
    __shared__ float red[4][64];

    const float* col = actv + (size_t)k * (BSZ * PP);

    for (int i = tid; i < BSZ * PP; i += 256) {    // 2560 floats, coalesced
        int rr = i / 5;
        sB[rr][i - rr * 5] = col[i];
    }

    const int b = bc * 64 + r;
    const float a0 = col[b * 5 + 0];
    const float a1 = col[b * 5 + 1];
    const float a2 = col[b * 5 + 2];
    const float a3 = col[b * 5 + 3];
    const float a4 = col[b * 5 + 4];
    __syncthreads();

    float acc0 = 0.f, acc1 = 0.f;
    const int j0 = seg * 128;
#pragma unroll 8
    for (int jj = 0; jj < 128; jj += 2) {
        const float4 v  = *(const float4*)&sB[j0 + jj][0];
        const float  v4 = sB[j0 + jj][4];
        float s = fabsf(a0 - v.x) + fabsf(a1 - v.y) + fabsf(a2 - v.z) +
                  fabsf(a3 - v.w) + fabsf(a4 - v4);
        acc0 += __builtin_amdgcn_exp2f(-s);
        const float4 w  = *(const float4*)&sB[j0 + jj + 1][0];
        const float  w4 = sB[j0 + jj + 1][4];
        float t = fabsf(a0 - w.x) + fabsf(a1 - w.y) + fabsf(a2 - w.z) +
                  fabsf(a3 - w.w) + fabsf(a4 - w4);
        acc1 += __builtin_amdgcn_exp2f(-t);
    }
    red[seg][r] = acc0 + acc1;
    __syncthreads();
    if (tid < 64) {
        float s = red[0][tid] + red[1][tid] + red[2][tid] + red[3][tid];
        out[(size_t)(bc * 64 + tid) * OUTW + DD + k] = s - 1.0f + bias[k];
    }
}

// ---------------------------------------------------------------------------
extern "C" void kernel_launch(void* const* d_in, const int* in_sizes, int n_in,
                              void* d_out, int out_size, void* d_ws, size_t ws_size,
                              hipStream_t stream) {
    const float* x     = (const float*)d_in[0];   // [512, 2048]
    const float* theta = (const float*)d_in[1];   // [2048, 128, 5]
    const float* lws   = (const float*)d_in[2];   // [128, 5]
    const float* bias  = (const float*)d_in[3];   // [128]
    float* out = (float*)d_out;                   // [512, 2176]

    float* ws     = (float*)d_ws;
    float* norm   = ws + WS_NORM;
    float* actv   = ws + WS_ACTV;
    ushort* xb    = (ushort*)(ws + WS_XB);
    ushort* thT   = (ushort*)(ws + WS_THT);
    ushort* parth = (ushort*)(ws + WS_PART);

    prep_kernel<<<656, 256, 0, stream>>>(theta, x, norm, thT, xb);
    gemm_kernel<<<1360, 256, 0, stream>>>(xb, thT, parth, x, out);
    reduce_kernel<<<640, 256, 0, stream>>>(parth, norm, lws, actv);
    pairwise_kernel<<<dim3(KK, 8), 256, 0, stream>>>(actv, bias, out);
}

// Round 11
// 100.707 us; speedup vs baseline: 1.0136x; 1.0136x over previous
//
#include <hip/hip_runtime.h>
#include <math.h>

#define BSZ 512
#define DD 2048
#define KK 128
#define PP 5
#define NCOL (KK * PP)   // 640
#define OUTW (DD + KK)   // 2176
#define LOG2E 1.4426950408889634f

#define KSPLIT 16
#define GK (DD / KSPLIT) // 128 k-depth per split

typedef __attribute__((ext_vector_type(8))) short bf16x8;
typedef __attribute__((ext_vector_type(4))) float f32x4;

// ws layout (floats):
#define WS_NORM 0
#define WS_ACTV (WS_NORM + NCOL)                      // 640  (b-major [512][640])
#define WS_XB (WS_ACTV + BSZ * NCOL)                  // 328320 (512*2048 ushort)
#define WS_THT (WS_XB + BSZ * DD / 2)                 // 852608 (640*2048 ushort)
#define WS_PART (WS_THT + NCOL * DD / 2)              // 1507968 (16*512*640 ushort)

__device__ inline ushort f2b(float f) {               // f32 -> bf16 RNE
    unsigned u = __float_as_uint(f);
    u += 0x7FFF + ((u >> 16) & 1);
    return (ushort)(u >> 16);
}

// XOR-swizzled LDS index (ushort units).
#define SWZ(r, c) ((((r) * 128) + ((c) ^ (((r) & 7) << 3))))

// ---------------------------------------------------------------------------
// Kernel 1 (prep): [0,80) norm = colsum theta^2; [80,400) theta -> bf16
// transposed [640 n][2048 k]; [400,656) x -> bf16 [512][2048].
// ---------------------------------------------------------------------------
__global__ __launch_bounds__(256) void prep_kernel(const float* __restrict__ theta,
                                                   const float* __restrict__ x,
                                                   float* __restrict__ norm,
                                                   ushort* __restrict__ thT,
                                                   ushort* __restrict__ xb) {
    __shared__ float partial[32][8];
    __shared__ ushort sT[64][68];   // [n][k] tile; stride 68: write 8-way, read 2-way

    const int bid = blockIdx.x;
    const int t   = threadIdx.x;

    if (bid < 80) {                 // ---- norm ----
        const int c8  = bid * 8;
        const int col = c8 + (t & 7);
        const int g   = t >> 3;
        const float* p = theta + (size_t)g * NCOL + col;
        float s = 0.f;
#pragma unroll
        for (int j = 0; j < 64; ++j) {
            float v = p[(size_t)j * 32 * NCOL];
            s += v * v;
        }
        partial[g][t & 7] = s;
        __syncthreads();
        if (t < 8) {
            float acc = 0.f;
#pragma unroll
            for (int gg = 0; gg < 32; ++gg) acc += partial[gg][t];
            norm[c8 + t] = acc;
        }
    } else if (bid < 400) {         // ---- theta transpose+convert, 64x64 tiles ----
        const int tb    = bid - 80;        // 0..319 = 32 ktiles x 10 ntiles
        const int kz    = (tb & 31) * 64;
        const int nz    = (tb >> 5) * 64;
        const int c4    = t & 15;          // n-quad
        const int rbase = t >> 4;          // k-row base
#pragma unroll
        for (int i = 0; i < 4; ++i) {
            int r = rbase + i * 16;
            float4 v = *(const float4*)&theta[(size_t)(kz + r) * NCOL + nz + c4 * 4];
            sT[c4 * 4 + 0][r] = f2b(v.x);
            sT[c4 * 4 + 1][r] = f2b(v.y);
            sT[c4 * 4 + 2][r] = f2b(v.z);
            sT[c4 * 4 + 3][r] = f2b(v.w);
        }
        __syncthreads();
#pragma unroll
        for (int i = 0; i < 2; ++i) {
            int slot = t + i * 256;
            int rr   = slot >> 3;          // n row 0..63
            int cc   = (slot & 7) * 8;     // k col
            ushort4 w0 = *(const ushort4*)&sT[rr][cc];
            ushort4 w1 = *(const ushort4*)&sT[rr][cc + 4];
            ushort* dst = &thT[(size_t)(nz + rr) * DD + kz + cc];
            *(ushort4*)&dst[0] = w0;
            *(ushort4*)&dst[4] = w1;
        }
    } else {                        // ---- x convert ----
        const int b2 = bid - 400;          // 0..255
#pragma unroll
        for (int i = 0; i < 4; ++i) {
            int base = b2 * 4096 + i * 1024 + t * 4;
            float4 v = *(const float4*)&x[base];
            ushort4 w;
            w.x = f2b(v.x); w.y = f2b(v.y); w.z = f2b(v.z); w.w = f2b(v.w);
            *(ushort4*)&xb[base] = w;
        }
    }
}

// ---------------------------------------------------------------------------
// Kernel 2: split-K MFMA GEMM, ONE chunk per block (1280 blocks = 5/CU all
// resident; r7-verified). XCD swizzle: m-tile = bid&7 -> per-XCD set 2.75MB
// < 4MB L2. part stored bf16 (r8-verified, absmax unchanged).
// Blocks [1280,1360): x -> out[:, :D] copy.
// ---------------------------------------------------------------------------
__global__ __launch_bounds__(256) void gemm_kernel(const ushort* __restrict__ xb,
                                                   const ushort* __restrict__ thT,
                                                   ushort* __restrict__ parth,
                                                   const float* __restrict__ x,
                                                   float* __restrict__ out) {
    __shared__ ushort lA[64 * 128];   // 16 KiB, swizzled
    __shared__ ushort lB[64 * 128];

    const int bx = blockIdx.x;
    if (bx >= 1280) {
        const int bid = bx - 1280;      // 0..79
        for (int i = bid * 256 + threadIdx.x; i < BSZ * (DD / 4); i += 80 * 256) {
            int r = i >> 9;
            int c = i & 511;
            float4 v = *(const float4*)&x[(size_t)r * DD + c * 4];
            *(float4*)&out[(size_t)r * OUTW + c * 4] = v;
        }
        return;
    }

    const int t    = threadIdx.x;
    const int lane = t & 63;
    const int wave = t >> 6;
    const int mt8  = bx & 7;           // m-tile -> XCD affinity
    const int rest = bx >> 3;          // 0..159
    const int bn   = (rest % 10) * 64;
    const int bm   = mt8 * 64;
    const int z    = rest / 10;        // 0..15
    const int kz   = z * GK;

    const ushort* gA = xb  + (size_t)bm * DD + kz;
    const ushort* gB = thT + (size_t)bn * DD + kz;

    const int srr = t >> 4;          // staging row base
    const int sss = t & 15;          // staging slot

    uint4 va[4], vb[4];
#pragma unroll
    for (int i = 0; i < 4; ++i) {
        int rr = srr + i * 16;
        va[i] = *(const uint4*)&gA[(size_t)rr * DD + sss * 8];
        vb[i] = *(const uint4*)&gB[(size_t)rr * DD + sss * 8];
    }
#pragma unroll
    for (int i = 0; i < 4; ++i) {
        int rr = srr + i * 16;
        *(uint4*)&lA[SWZ(rr, sss * 8)] = va[i];
        *(uint4*)&lB[SWZ(rr, sss * 8)] = vb[i];
    }
    __syncthreads();

    const int fr = lane & 15;
    const int g  = lane >> 4;
    const int mr = (wave >> 1) * 32 + fr;
    const int nr = (wave & 1) * 32 + fr;

    f32x4 acc[2][2] = {};
#pragma unroll
    for (int ks = 0; ks < 4; ++ks) {
        const int kc = ks * 32 + g * 8;
        bf16x8 a0 = *(const bf16x8*)&lA[SWZ(mr,      kc)];
        bf16x8 a1 = *(const bf16x8*)&lA[SWZ(mr + 16, kc)];
        bf16x8 b0 = *(const bf16x8*)&lB[SWZ(nr,      kc)];
        bf16x8 b1 = *(const bf16x8*)&lB[SWZ(nr + 16, kc)];
        acc[0][0] = __builtin_amdgcn_mfma_f32_16x16x32_bf16(a0, b0, acc[0][0], 0, 0, 0);
        acc[0][1] = __builtin_amdgcn_mfma_f32_16x16x32_bf16(a0, b1, acc[0][1], 0, 0, 0);
        acc[1][0] = __builtin_amdgcn_mfma_f32_16x16x32_bf16(a1, b0, acc[1][0], 0, 0, 0);
        acc[1][1] = __builtin_amdgcn_mfma_f32_16x16x32_bf16(a1, b1, acc[1][1], 0, 0, 0);
    }

    // C/D map: col=lane&15, row=(lane>>4)*4+reg [m89-verified]
    ushort* base = parth + (size_t)z * (BSZ * NCOL);
#pragma unroll
    for (int mt = 0; mt < 2; ++mt)
#pragma unroll
        for (int nt = 0; nt < 2; ++nt) {
            int row = bm + (wave >> 1) * 32 + mt * 16 + g * 4;
            int col = bn + (wave & 1) * 32 + nt * 16 + fr;
            ushort* dst = base + (size_t)row * NCOL + col;
#pragma unroll
            for (int reg = 0; reg < 4; ++reg)
                dst[(size_t)reg * NCOL] = f2b(acc[mt][nt][reg]);
        }
}

// ---------------------------------------------------------------------------
// Kernel 3: reduce 16 bf16 split-K partials (ushort2 reads), fold scale,
// b-major actv [512][640] (coalesced float2 writes; r10's [k]-major scatter
// write cost ~1-2us -- reverted).
// ---------------------------------------------------------------------------
__global__ __launch_bounds__(256) void reduce_kernel(const ushort* __restrict__ parth,
                                                     const float* __restrict__ norm,
                                                     const float* __restrict__ lws,
                                                     float* __restrict__ actv) {
    int i = (blockIdx.x * 256 + threadIdx.x) * 2;   // 0..655358 step 2
    float s0 = 0.f, s1 = 0.f;
#pragma unroll
    for (int q = 0; q < KSPLIT; ++q) {
        unsigned u = *(const unsigned*)&parth[(size_t)q * (BSZ * NCOL) + i];
        s0 += __uint_as_float(u << 16);
        s1 += __uint_as_float(u & 0xffff0000u);
    }
    const int col = i % NCOL;       // even; col+1 < 640
    const float sc0 = __builtin_amdgcn_exp2f(lws[col] * LOG2E) *
                      __builtin_amdgcn_rsqf(norm[col]) * LOG2E;
    const float sc1 = __builtin_amdgcn_exp2f(lws[col + 1] * LOG2E) *
                      __builtin_amdgcn_rsqf(norm[col + 1]) * LOG2E;
    float2 o = make_float2(s0 * sc0, s1 * sc1);
    *(float2*)&actv[i] = o;
}

// ---------------------------------------------------------------------------
// Kernel 4: pairwise, R=2 rows/thread. Measured model: bound by per-CU LDS
// issue pipe at 18 cyc/j/wave (r10 = 15.4us at R=1). Block (k, rc): 128 rows,
// 4 waves x 128-j segments; each thread's 2 DS reads/j feed 2 rows -> DS/CU
// halves to ~7.7us, VALU ~7.3us/SIMD at 8 waves/CU (512 blocks, 2/CU).
// Wave-partials LDS-reduced; writes out[:, D+k] directly (+bias, -1 diag).
// ---------------------------------------------------------------------------
__global__ __launch_bounds__(256) void pairwise_kernel(const float* __restrict__ actv,
                                                       const float* __restrict__ bias,
                                                       float* __restrict__ out) {
    const int k    = blockIdx.x;    // 0..127
    const int rc   = blockIdx.y;    // 0..3
    const int tid  = threadIdx.x;   // 0..255
    const int lane = tid & 63;
    const int seg  = tid >> 6;      // wave = j-segment

    __shared__ float sB[512][8];    // 16 KiB, rows 32B-aligned
    __shared__ float red[4][128];

    // stage k-column for all 512 rows (10KB, strided 20B reads, L2-served)
    for (int i = tid; i < BSZ * PP; i += 256) {
        int rr = i / 5;
        int p  = i - rr * 5;
        sB[rr][p] = actv[(size_t)rr * NCOL + k * PP + p];
    }

    const int r0 = rc * 128 + lane;     // thread's 2 rows
    const int r1 = r0 + 64;
    float a0[PP], a1[PP];
#pragma unroll
    for (int p = 0; p < PP; ++p) {
        a0[p] = actv[(size_t)r0 * NCOL + k * PP + p];
        a1[p] = actv[(size_t)r1 * NCOL + k * PP + p];
    }
    __syncthreads();

    float acc0 = 0.f, acc1 = 0.f;
    const int j0 = seg * 128;
#pragma unroll 4
    for (int jj = 0; jj < 128; ++jj) {
        const float4 v  = *(const float4*)&sB[j0 + jj][0];
        const float  v4 = sB[j0 + jj][4];
        float s = fabsf(a0[0] - v.x) + fabsf(a0[1] - v.y) + fabsf(a0[2] - v.z) +
                  fabsf(a0[3] - v.w) + fabsf(a0[4] - v4);
        acc0 += __builtin_amdgcn_exp2f(-s);
        float t = fabsf(a1[0] - v.x) + fabsf(a1[1] - v.y) + fabsf(a1[2] - v.z) +
                  fabsf(a1[3] - v.w) + fabsf(a1[4] - v4);
        acc1 += __builtin_amdgcn_exp2f(-t);
    }
    red[seg][lane]      = acc0;
    red[seg][lane + 64] = acc1;
    __syncthreads();

    if (tid < 128) {
        float s = red[0][tid] + red[1][tid] + red[2][tid] + red[3][tid];
        out[(size_t)(rc * 128 + tid) * OUTW + DD + k] = s - 1.0f + bias[k];
    }
}

// ---------------------------------------------------------------------------
extern "C" void kernel_launch(void* const* d_in, const int* in_sizes, int n_in,
                              void* d_out, int out_size, void* d_ws, size_t ws_size,
                              hipStream_t stream) {
    const float* x     = (const float*)d_in[0];   // [512, 2048]
    const float* theta = (const float*)d_in[1];   // [2048, 128, 5]
    const float* lws   = (const float*)d_in[2];   // [128, 5]
    const float* bias  = (const float*)d_in[3];   // [128]
    float* out = (float*)d_out;                   // [512, 2176]

    float* ws     = (float*)d_ws;
    float* norm   = ws + WS_NORM;
    float* actv   = ws + WS_ACTV;
    ushort* xb    = (ushort*)(ws + WS_XB);
    ushort* thT   = (ushort*)(ws + WS_THT);
    ushort* parth = (ushort*)(ws + WS_PART);

    prep_kernel<<<656, 256, 0, stream>>>(theta, x, norm, thT, xb);
    gemm_kernel<<<1360, 256, 0, stream>>>(xb, thT, parth, x, out);
    reduce_kernel<<<640, 256, 0, stream>>>(parth, norm, lws, actv);
    pairwise_kernel<<<dim3(KK, 4), 256, 0, stream>>>(actv, bias, out);
}

// Round 12
// 100.132 us; speedup vs baseline: 1.0194x; 1.0057x over previous
//
#include <hip/hip_runtime.h>
#include <math.h>

#define BSZ 512
#define DD 2048
#define KK 128
#define PP 5
#define NCOL (KK * PP)   // 640
#define OUTW (DD + KK)   // 2176
#define LOG2E 1.4426950408889634f

#define KSPLIT 16
#define GK (DD / KSPLIT) // 128 k-depth per split

typedef __attribute__((ext_vector_type(8))) short bf16x8;
typedef __attribute__((ext_vector_type(4))) float f32x4;

// ws layout (floats):
#define WS_NORM 0
#define WS_ACTV (WS_NORM + NCOL)                      // 640  (k-major [128][512][5])
#define WS_XB (WS_ACTV + BSZ * NCOL)                  // 328320 (512*2048 ushort)
#define WS_THT (WS_XB + BSZ * DD / 2)                 // 852608 (640*2048 ushort)
#define WS_PART (WS_THT + NCOL * DD / 2)              // 1507968 (16*512*640 ushort)

__device__ inline ushort f2b(float f) {               // f32 -> bf16 RNE
    unsigned u = __float_as_uint(f);
    u += 0x7FFF + ((u >> 16) & 1);
    return (ushort)(u >> 16);
}

// XOR-swizzled LDS index (ushort units). SQ_LDS_BANK_CONFLICT=256/block is
// the benign 2-way-alias count (free, m136) -- verified r5/r6 invariant.
#define SWZ(r, c) ((((r) * 128) + ((c) ^ (((r) & 7) << 3))))

// ---------------------------------------------------------------------------
// Kernel 1 (prep): [0,80) norm = colsum theta^2; [80,400) theta -> bf16
// transposed [640 n][2048 k]; [400,656) x -> bf16 [512][2048].
// ---------------------------------------------------------------------------
__global__ __launch_bounds__(256) void prep_kernel(const float* __restrict__ theta,
                                                   const float* __restrict__ x,
                                                   float* __restrict__ norm,
                                                   ushort* __restrict__ thT,
                                                   ushort* __restrict__ xb) {
    __shared__ float partial[32][8];
    __shared__ ushort sT[64][68];   // [n][k] tile; stride 68: write 8-way, read 2-way

    const int bid = blockIdx.x;
    const int t   = threadIdx.x;

    if (bid < 80) {                 // ---- norm ----
        const int c8  = bid * 8;
        const int col = c8 + (t & 7);
        const int g   = t >> 3;
        const float* p = theta + (size_t)g * NCOL + col;
        float s = 0.f;
#pragma unroll
        for (int j = 0; j < 64; ++j) {
            float v = p[(size_t)j * 32 * NCOL];
            s += v * v;
        }
        partial[g][t & 7] = s;
        __syncthreads();
        if (t < 8) {
            float acc = 0.f;
#pragma unroll
            for (int gg = 0; gg < 32; ++gg) acc += partial[gg][t];
            norm[c8 + t] = acc;
        }
    } else if (bid < 400) {         // ---- theta transpose+convert, 64x64 tiles ----
        const int tb    = bid - 80;        // 0..319 = 32 ktiles x 10 ntiles
        const int kz    = (tb & 31) * 64;
        const int nz    = (tb >> 5) * 64;
        const int c4    = t & 15;          // n-quad
        const int rbase = t >> 4;          // k-row base
#pragma unroll
        for (int i = 0; i < 4; ++i) {
            int r = rbase + i * 16;
            float4 v = *(const float4*)&theta[(size_t)(kz + r) * NCOL + nz + c4 * 4];
            sT[c4 * 4 + 0][r] = f2b(v.x);
            sT[c4 * 4 + 1][r] = f2b(v.y);
            sT[c4 * 4 + 2][r] = f2b(v.z);
            sT[c4 * 4 + 3][r] = f2b(v.w);
        }
        __syncthreads();
#pragma unroll
        for (int i = 0; i < 2; ++i) {
            int slot = t + i * 256;
            int rr   = slot >> 3;          // n row 0..63
            int cc   = (slot & 7) * 8;     // k col
            ushort4 w0 = *(const ushort4*)&sT[rr][cc];
            ushort4 w1 = *(const ushort4*)&sT[rr][cc + 4];
            ushort* dst = &thT[(size_t)(nz + rr) * DD + kz + cc];
            *(ushort4*)&dst[0] = w0;
            *(ushort4*)&dst[4] = w1;
        }
    } else {                        // ---- x convert ----
        const int b2 = bid - 400;          // 0..255
#pragma unroll
        for (int i = 0; i < 4; ++i) {
            int base = b2 * 4096 + i * 1024 + t * 4;
            float4 v = *(const float4*)&x[base];
            ushort4 w;
            w.x = f2b(v.x); w.y = f2b(v.y); w.z = f2b(v.z); w.w = f2b(v.w);
            *(ushort4*)&xb[base] = w;
        }
    }
}

// ---------------------------------------------------------------------------
// Kernel 2: split-K MFMA GEMM, ONE chunk per block (1280 blocks = 5/CU all
// resident; r7-verified). XCD swizzle: m-tile = bid&7 -> per-XCD set 2.75MB
// < 4MB L2. part stored bf16 (r8-verified, absmax unchanged).
// Blocks [1280,1360): x -> out[:, :D] copy.
// ---------------------------------------------------------------------------
__global__ __launch_bounds__(256) void gemm_kernel(const ushort* __restrict__ xb,
                                                   const ushort* __restrict__ thT,
                                                   ushort* __restrict__ parth,
                                                   const float* __restrict__ x,
                                                   float* __restrict__ out) {
    __shared__ ushort lA[64 * 128];   // 16 KiB, swizzled
    __shared__ ushort lB[64 * 128];

    const int bx = blockIdx.x;
    if (bx >= 1280) {
        const int bid = bx - 1280;      // 0..79
        for (int i = bid * 256 + threadIdx.x; i < BSZ * (DD / 4); i += 80 * 256) {
            int r = i >> 9;
            int c = i & 511;
            float4 v = *(const float4*)&x[(size_t)r * DD + c * 4];
            *(float4*)&out[(size_t)r * OUTW + c * 4] = v;
        }
        return;
    }

    const int t    = threadIdx.x;
    const int lane = t & 63;
    const int wave = t >> 6;
    const int mt8  = bx & 7;           // m-tile -> XCD affinity
    const int rest = bx >> 3;          // 0..159
    const int bn   = (rest % 10) * 64;
    const int bm   = mt8 * 64;
    const int z    = rest / 10;        // 0..15
    const int kz   = z * GK;

    const ushort* gA = xb  + (size_t)bm * DD + kz;
    const ushort* gB = thT + (size_t)bn * DD + kz;

    const int srr = t >> 4;          // staging row base
    const int sss = t & 15;          // staging slot

    uint4 va[4], vb[4];
#pragma unroll
    for (int i = 0; i < 4; ++i) {
        int rr = srr + i * 16;
        va[i] = *(const uint4*)&gA[(size_t)rr * DD + sss * 8];
        vb[i] = *(const uint4*)&gB[(size_t)rr * DD + sss * 8];
    }
#pragma unroll
    for (int i = 0; i < 4; ++i) {
        int rr = srr + i * 16;
        *(uint4*)&lA[SWZ(rr, sss * 8)] = va[i];
        *(uint4*)&lB[SWZ(rr, sss * 8)] = vb[i];
    }
    __syncthreads();

    const int fr = lane & 15;
    const int g  = lane >> 4;
    const int mr = (wave >> 1) * 32 + fr;
    const int nr = (wave & 1) * 32 + fr;

    f32x4 acc[2][2] = {};
#pragma unroll
    for (int ks = 0; ks < 4; ++ks) {
        const int kc = ks * 32 + g * 8;
        bf16x8 a0 = *(const bf16x8*)&lA[SWZ(mr,      kc)];
        bf16x8 a1 = *(const bf16x8*)&lA[SWZ(mr + 16, kc)];
        bf16x8 b0 = *(const bf16x8*)&lB[SWZ(nr,      kc)];
        bf16x8 b1 = *(const bf16x8*)&lB[SWZ(nr + 16, kc)];
        acc[0][0] = __builtin_amdgcn_mfma_f32_16x16x32_bf16(a0, b0, acc[0][0], 0, 0, 0);
        acc[0][1] = __builtin_amdgcn_mfma_f32_16x16x32_bf16(a0, b1, acc[0][1], 0, 0, 0);
        acc[1][0] = __builtin_amdgcn_mfma_f32_16x16x32_bf16(a1, b0, acc[1][0], 0, 0, 0);
        acc[1][1] = __builtin_amdgcn_mfma_f32_16x16x32_bf16(a1, b1, acc[1][1], 0, 0, 0);
    }

    // C/D map: col=lane&15, row=(lane>>4)*4+reg [m89-verified]
    ushort* base = parth + (size_t)z * (BSZ * NCOL);
#pragma unroll
    for (int mt = 0; mt < 2; ++mt)
#pragma unroll
        for (int nt = 0; nt < 2; ++nt) {
            int row = bm + (wave >> 1) * 32 + mt * 16 + g * 4;
            int col = bn + (wave & 1) * 32 + nt * 16 + fr;
            ushort* dst = base + (size_t)row * NCOL + col;
#pragma unroll
            for (int reg = 0; reg < 4; ++reg)
                dst[(size_t)reg * NCOL] = f2b(acc[mt][nt][reg]);
        }
}

// ---------------------------------------------------------------------------
// Kernel 3: reduce 16 bf16 split-K partials (ushort2 coalesced reads), fold
// scale, write actv k-major [k][512][5] -- pairwise (the only consumer)
// then stages fully coalesced. Scattered 4B writes are L2-absorbed
// (~+0.5us, r10 data), traded for coalesced pairwise staging.
// ---------------------------------------------------------------------------
__global__ __launch_bounds__(256) void reduce_kernel(const ushort* __restrict__ parth,
                                                     const float* __restrict__ norm,
                                                     const float* __restrict__ lws,
                                                     float* __restrict__ actv) {
    int i   = (blockIdx.x * 256 + threadIdx.x) * 2;   // b-major input idx
    int b   = i / NCOL;
    int col = i - b * NCOL;                            // even
    float s0 = 0.f, s1 = 0.f;
#pragma unroll
    for (int q = 0; q < KSPLIT; ++q) {
        unsigned u = *(const unsigned*)&parth[(size_t)q * (BSZ * NCOL) + i];
        s0 += __uint_as_float(u << 16);
        s1 += __uint_as_float(u & 0xffff0000u);
    }
    const float sc0 = __builtin_amdgcn_exp2f(lws[col] * LOG2E) *
                      __builtin_amdgcn_rsqf(norm[col]) * LOG2E;
    const float sc1 = __builtin_amdgcn_exp2f(lws[col + 1] * LOG2E) *
                      __builtin_amdgcn_rsqf(norm[col + 1]) * LOG2E;
    int k0 = col / 5,       p0 = col - k0 * 5;
    int k1 = (col + 1) / 5, p1 = (col + 1) - k1 * 5;
    actv[((size_t)k0 * BSZ + b) * PP + p0] = s0 * sc0;
    actv[((size_t)k1 * BSZ + b) * PP + p1] = s1 * sc1;
}

// ---------------------------------------------------------------------------
// Kernel 4: pairwise, R=4 rows/thread. 256 blocks (1/CU) x 512 threads
// (8 waves = 2/SIMD). Block (k, rc): 256 rows x ALL 512 j (8 wave-segments
// x 64 j). Per j: 2 broadcast DS reads feed 4 rows -> DS/CU ~1.9us
// (non-binding); VALU/SIMD ~8-9us is the floor. All row data read from the
// staged LDS column (no strided global). Writes out[:, D+k] directly.
// ---------------------------------------------------------------------------
__global__ __launch_bounds__(512) void pairwise_kernel(const float* __restrict__ actv,
                                                       const float* __restrict__ bias,
                                                       float* __restrict__ out) {
    const int k    = blockIdx.x;    // 0..127
    const int rc   = blockIdx.y;    // 0..1
    const int tid  = threadIdx.x;   // 0..511
    const int lane = tid & 63;
    const int seg  = tid >> 6;      // wave = j-segment 0..7

    __shared__ float sB[512][8];    // 16 KiB, rows 32B-aligned
    __shared__ float red[8][256];   // 8 KiB

    // stage full k-column (10KB contiguous): 5 coalesced loads/thread
    const float* col = actv + (size_t)k * (BSZ * PP);
    for (int i = tid; i < BSZ * PP; i += 512) {
        int rr = i / 5;
        sB[rr][i - rr * 5] = col[i];
    }
    __syncthreads();

    // own 4 rows from LDS (one-time, conflict cost negligible)
    const int r0 = rc * 256 + lane;
    float a[4][PP];
#pragma unroll
    for (int r = 0; r < 4; ++r)
#pragma unroll
        for (int p = 0; p < PP; ++p)
            a[r][p] = sB[r0 + r * 64][p];

    float acc[4] = {0.f, 0.f, 0.f, 0.f};
    const int j0 = seg * 64;
#pragma unroll 4
    for (int jj = 0; jj < 64; ++jj) {
        const float4 v  = *(const float4*)&sB[j0 + jj][0];
        const float  v4 = sB[j0 + jj][4];
#pragma unroll
        for (int r = 0; r < 4; ++r) {
            float s = fabsf(a[r][0] - v.x) + fabsf(a[r][1] - v.y) +
                      fabsf(a[r][2] - v.z) + fabsf(a[r][3] - v.w) +
                      fabsf(a[r][4] - v4);
            acc[r] += __builtin_amdgcn_exp2f(-s);   // actv pre-scaled by log2e
        }
    }
#pragma unroll
    for (int r = 0; r < 4; ++r)
        red[seg][lane + r * 64] = acc[r];
    __syncthreads();

    if (tid < 256) {
        float s = red[0][tid] + red[1][tid] + red[2][tid] + red[3][tid] +
                  red[4][tid] + red[5][tid] + red[6][tid] + red[7][tid];
        out[(size_t)(rc * 256 + tid) * OUTW + DD + k] = s - 1.0f + bias[k];
    }
}

// ---------------------------------------------------------------------------
extern "C" void kernel_launch(void* const* d_in, const int* in_sizes, int n_in,
                              void* d_out, int out_size, void* d_ws, size_t ws_size,
                              hipStream_t stream) {
    const float* x     = (const float*)d_in[0];   // [512, 2048]
    const float* theta = (const float*)d_in[1];   // [2048, 128, 5]
    const float* lws   = (const float*)d_in[2];   // [128, 5]
    const float* bias  = (const float*)d_in[3];   // [128]
    float* out = (float*)d_out;                   // [512, 2176]

    float* ws     = (float*)d_ws;
    float* norm   = ws + WS_NORM;
    float* actv   = ws + WS_ACTV;
    ushort* xb    = (ushort*)(ws + WS_XB);
    ushort* thT   = (ushort*)(ws + WS_THT);
    ushort* parth = (ushort*)(ws + WS_PART);

    prep_kernel<<<656, 256, 0, stream>>>(theta, x, norm, thT, xb);
    gemm_kernel<<<1360, 256, 0, stream>>>(xb, thT, parth, x, out);
    reduce_kernel<<<640, 256, 0, stream>>>(parth, norm, lws, actv);
    pairwise_kernel<<<dim3(KK, 2), 512, 0, stream>>>(actv, bias, out);
}